// Round 1
// baseline (294.566 us; speedup 1.0000x reference)
//
#include <hip/hip_runtime.h>

typedef __attribute__((ext_vector_type(8))) short bf16x8;
typedef __attribute__((ext_vector_type(4))) float f32x4;

#define D_DIM 256
#define NROW  8192

__device__ __forceinline__ unsigned short f2bf(float x) {
  unsigned int u = __float_as_uint(x);
  u += 0x7fffu + ((u >> 16) & 1u);   // round-to-nearest-even
  return (unsigned short)(u >> 16);
}

__device__ __forceinline__ void gload_lds16(const void* g, void* l) {
  __builtin_amdgcn_global_load_lds((__attribute__((address_space(1))) void*)g,
                                   (__attribute__((address_space(3))) void*)l,
                                   16, 0, 0);
}

// One wave per row (D=256 -> 4 floats/lane). fp32 softmax, bf16 output.
__global__ __launch_bounds__(256) void softmax_rows(const float* __restrict__ S,
                                                    unsigned short* __restrict__ P) {
  const int row  = blockIdx.x * 4 + (threadIdx.x >> 6);
  const int lane = threadIdx.x & 63;
  float4 v = ((const float4*)(S + row * D_DIM))[lane];
  float m = fmaxf(fmaxf(v.x, v.y), fmaxf(v.z, v.w));
#pragma unroll
  for (int off = 32; off > 0; off >>= 1) m = fmaxf(m, __shfl_xor(m, off));
  float e0 = __expf(v.x - m), e1 = __expf(v.y - m);
  float e2 = __expf(v.z - m), e3 = __expf(v.w - m);
  float s = e0 + e1 + e2 + e3;
#pragma unroll
  for (int off = 32; off > 0; off >>= 1) s += __shfl_xor(s, off);
  const float inv = 1.0f / s;
  ushort4 o;
  o.x = f2bf(e0 * inv); o.y = f2bf(e1 * inv);
  o.z = f2bf(e2 * inv); o.w = f2bf(e3 * inv);
  ((ushort4*)(P + row * D_DIM))[lane] = o;
}

__global__ __launch_bounds__(256) void cast_v(const float* __restrict__ V,
                                              unsigned short* __restrict__ Vb) {
  const int i = blockIdx.x * 256 + threadIdx.x;  // one float4 per thread
  float4 v = ((const float4*)V)[i];
  ushort4 o;
  o.x = f2bf(v.x); o.y = f2bf(v.y); o.z = f2bf(v.z); o.w = f2bf(v.w);
  ((ushort4*)Vb)[i] = o;
}

// NT GEMM: O[i,j] = sum_k P[i,k] * Vb[j,k].  128x128 tile, BK=32,
// 4 waves in 2x2, each wave 64x64 via 4x4 grid of 16x16x32 MFMAs.
__global__ __launch_bounds__(256) void gemm_bt(const unsigned short* __restrict__ P,
                                               const unsigned short* __restrict__ Vb,
                                               float* __restrict__ O) {
  __shared__ unsigned short As[128 * 32];
  __shared__ unsigned short Bs[128 * 32];

  const int t    = threadIdx.x;
  const int lane = t & 63;
  const int wave = t >> 6;
  const int wm   = (wave & 1) * 64;
  const int wn   = (wave >> 1) * 64;
  const int bm   = blockIdx.x;
  const int bn   = blockIdx.y;

  f32x4 acc[4][4] = {};

  // staging: thread t loads 16B at rows t/4 and t/4+64, col-bytes (t%4)*16.
  // LDS byte offset = t*16 (+4096) -> wave-uniform base + lane*16. [G5 constraint]
  const int srow = t >> 2;
  const int scol = (t & 3) * 8;
  const unsigned short* ga = P  + (bm * 128 + srow) * D_DIM + scol;
  const unsigned short* gb = Vb + (bn * 128 + srow) * D_DIM + scol;
  unsigned short* la = As + srow * 32 + scol;
  unsigned short* lb = Bs + srow * 32 + scol;

  // fragment addressing: A[m=lane&15][k=(lane>>4)*8 + j]
  const int arow = wm + (lane & 15);
  const int brow = wn + (lane & 15);
  const int koff = (lane >> 4) * 8;

  for (int k0 = 0; k0 < D_DIM; k0 += 32) {
    gload_lds16(ga + k0,              la);
    gload_lds16(ga + 64 * D_DIM + k0, la + 64 * 32);
    gload_lds16(gb + k0,              lb);
    gload_lds16(gb + 64 * D_DIM + k0, lb + 64 * 32);
    __syncthreads();   // compiler emits vmcnt(0) drain before s_barrier

    bf16x8 af[4], bfr[4];
#pragma unroll
    for (int mi = 0; mi < 4; ++mi)
      af[mi] = *(const bf16x8*)&As[(arow + mi * 16) * 32 + koff];
#pragma unroll
    for (int ni = 0; ni < 4; ++ni)
      bfr[ni] = *(const bf16x8*)&Bs[(brow + ni * 16) * 32 + koff];

#pragma unroll
    for (int mi = 0; mi < 4; ++mi)
#pragma unroll
      for (int ni = 0; ni < 4; ++ni)
        acc[mi][ni] = __builtin_amdgcn_mfma_f32_16x16x32_bf16(af[mi], bfr[ni],
                                                              acc[mi][ni], 0, 0, 0);
    __syncthreads();
  }

  // C/D layout: col = lane&15, row = (lane>>4)*4 + reg
  const int crow = bm * 128 + wm + (lane >> 4) * 4;
  const int ccol = bn * 128 + wn + (lane & 15);
#pragma unroll
  for (int mi = 0; mi < 4; ++mi)
#pragma unroll
    for (int ni = 0; ni < 4; ++ni) {
#pragma unroll
      for (int r = 0; r < 4; ++r)
        O[(crow + mi * 16 + r) * NROW + ccol + ni * 16] = acc[mi][ni][r];
    }
}

extern "C" void kernel_launch(void* const* d_in, const int* in_sizes, int n_in,
                              void* d_out, int out_size, void* d_ws, size_t ws_size,
                              hipStream_t stream) {
  const float* S = (const float*)d_in[0];   // [8192, 256] fp32
  const float* V = (const float*)d_in[1];   // [8192, 256] fp32
  float* O = (float*)d_out;                 // [8192, 8192] fp32

  unsigned short* P  = (unsigned short*)d_ws;          // 4 MB bf16 softmax(S)
  unsigned short* Vb = P + (size_t)NROW * D_DIM;       // 4 MB bf16 V

  softmax_rows<<<NROW / 4, 256, 0, stream>>>(S, P);
  cast_v<<<(NROW * D_DIM / 4) / 256, 256, 0, stream>>>(V, Vb);
  gemm_bt<<<dim3(NROW / 128, NROW / 128), 256, 0, stream>>>(P, Vb, O);
}

// Round 2
// 293.116 us; speedup vs baseline: 1.0049x; 1.0049x over previous
//
#include <hip/hip_runtime.h>

typedef __attribute__((ext_vector_type(8))) short bf16x8;
typedef __attribute__((ext_vector_type(4))) float f32x4;

#define D_DIM 256
#define NROW  8192

__device__ __forceinline__ unsigned short f2bf(float x) {
  unsigned int u = __float_as_uint(x);
  u += 0x7fffu + ((u >> 16) & 1u);   // round-to-nearest-even
  return (unsigned short)(u >> 16);
}

__device__ __forceinline__ void gload_lds16(const void* g, void* l) {
  __builtin_amdgcn_global_load_lds((__attribute__((address_space(1))) void*)g,
                                   (__attribute__((address_space(3))) void*)l,
                                   16, 0, 0);
}

// One wave per row (D=256 -> 4 floats/lane). fp32 softmax, bf16 output.
__global__ __launch_bounds__(256) void softmax_rows(const float* __restrict__ S,
                                                    unsigned short* __restrict__ P) {
  const int row  = blockIdx.x * 4 + (threadIdx.x >> 6);
  const int lane = threadIdx.x & 63;
  float4 v = ((const float4*)(S + row * D_DIM))[lane];
  float m = fmaxf(fmaxf(v.x, v.y), fmaxf(v.z, v.w));
#pragma unroll
  for (int off = 32; off > 0; off >>= 1) m = fmaxf(m, __shfl_xor(m, off));
  float e0 = __expf(v.x - m), e1 = __expf(v.y - m);
  float e2 = __expf(v.z - m), e3 = __expf(v.w - m);
  float s = e0 + e1 + e2 + e3;
#pragma unroll
  for (int off = 32; off > 0; off >>= 1) s += __shfl_xor(s, off);
  const float inv = 1.0f / s;
  ushort4 o;
  o.x = f2bf(e0 * inv); o.y = f2bf(e1 * inv);
  o.z = f2bf(e2 * inv); o.w = f2bf(e3 * inv);
  ((ushort4*)(P + row * D_DIM))[lane] = o;
}

__global__ __launch_bounds__(256) void cast_v(const float* __restrict__ V,
                                              unsigned short* __restrict__ Vb) {
  const int i = blockIdx.x * 256 + threadIdx.x;  // one float4 per thread
  float4 v = ((const float4*)V)[i];
  ushort4 o;
  o.x = f2bf(v.x); o.y = f2bf(v.y); o.z = f2bf(v.z); o.w = f2bf(v.w);
  ((ushort4*)Vb)[i] = o;
}

// NT GEMM: O[i,j] = sum_k P[i,k] * Vb[j,k].  128x128 tile, BK=32,
// 4 waves in 2x2, each wave 64x64 via 4x4 grid of 16x16x32 MFMAs.
// Epilogue: per-wave LDS transpose -> float4 coalesced stores (256B segments).
__global__ __launch_bounds__(256) void gemm_bt(const unsigned short* __restrict__ P,
                                               const unsigned short* __restrict__ Vb,
                                               float* __restrict__ O) {
  // 34816 B shared: K-loop staging (16 KB As+Bs) aliases the epilogue
  // transpose buffer (4 waves x 32 rows x 68-float padded stride).
  __shared__ float smem[8704];
  unsigned short* As = (unsigned short*)smem;          // 128*32 shorts = 8 KB
  unsigned short* Bs = (unsigned short*)smem + 4096;   // 128*32 shorts = 8 KB

  const int t    = threadIdx.x;
  const int lane = t & 63;
  const int wave = t >> 6;
  const int wm   = (wave & 1) * 64;
  const int wn   = (wave >> 1) * 64;
  const int bm   = blockIdx.x;
  const int bn   = blockIdx.y;

  f32x4 acc[4][4] = {};

  // staging: thread t loads 16B at rows t/4 and t/4+64, col-shorts (t%4)*8.
  // LDS dest = wave-uniform base + lane*16 (global_load_lds constraint).
  const int srow = t >> 2;
  const int scol = (t & 3) * 8;
  const unsigned short* ga = P  + (bm * 128 + srow) * D_DIM + scol;
  const unsigned short* gb = Vb + (bn * 128 + srow) * D_DIM + scol;
  unsigned short* la = As + srow * 32 + scol;
  unsigned short* lb = Bs + srow * 32 + scol;

  // fragment addressing: A[m=lane&15][k=(lane>>4)*8 + j]
  const int arow = wm + (lane & 15);
  const int brow = wn + (lane & 15);
  const int koff = (lane >> 4) * 8;

  for (int k0 = 0; k0 < D_DIM; k0 += 32) {
    gload_lds16(ga + k0,              la);
    gload_lds16(ga + 64 * D_DIM + k0, la + 64 * 32);
    gload_lds16(gb + k0,              lb);
    gload_lds16(gb + 64 * D_DIM + k0, lb + 64 * 32);
    __syncthreads();

    bf16x8 af[4], bfr[4];
#pragma unroll
    for (int mi = 0; mi < 4; ++mi)
      af[mi] = *(const bf16x8*)&As[(arow + mi * 16) * 32 + koff];
#pragma unroll
    for (int ni = 0; ni < 4; ++ni)
      bfr[ni] = *(const bf16x8*)&Bs[(brow + ni * 16) * 32 + koff];

#pragma unroll
    for (int mi = 0; mi < 4; ++mi)
#pragma unroll
      for (int ni = 0; ni < 4; ++ni)
        acc[mi][ni] = __builtin_amdgcn_mfma_f32_16x16x32_bf16(af[mi], bfr[ni],
                                                              acc[mi][ni], 0, 0, 0);
    __syncthreads();   // also protects epilogue's smem reuse on last iter
  }

  // ---- Epilogue: wave-local LDS transpose, then float4 stores ----
  // MFMA C/D layout: col = lane&15, row = (lane>>4)*4 + reg.
  // Per-wave buffer: 32 rows x 68 floats (pad +4 breaks bank aliasing).
  float* ep = smem + wave * 2176;
  const int qrow = (lane >> 4) * 4;          // 0,4,8,12
  const int qcol = lane & 15;
  const size_t orow0 = (size_t)(bm * 128 + wm);
  const int    ocol0 = bn * 128 + wn + (lane & 15) * 4;

#pragma unroll
  for (int p = 0; p < 2; ++p) {              // two 32-row passes
#pragma unroll
    for (int mi2 = 0; mi2 < 2; ++mi2) {
      const int mi = p * 2 + mi2;
      const int r0 = mi2 * 16 + qrow;
#pragma unroll
      for (int ni = 0; ni < 4; ++ni)
#pragma unroll
        for (int r = 0; r < 4; ++r)
          ep[(r0 + r) * 68 + ni * 16 + qcol] = acc[mi][ni][r];
    }
    // wave-local: ds_write -> ds_read same region is wave-ordered (lgkmcnt)
#pragma unroll
    for (int q = 0; q < 8; ++q) {
      const int rl = q * 4 + (lane >> 4);    // 0..31 within pass
      float4 vv = *(const float4*)&ep[rl * 68 + (lane & 15) * 4];
      *(float4*)&O[(orow0 + p * 32 + rl) * NROW + ocol0] = vv;
    }
    if (p == 0) __syncthreads();             // cheap; keeps waves in lockstep
  }
}

extern "C" void kernel_launch(void* const* d_in, const int* in_sizes, int n_in,
                              void* d_out, int out_size, void* d_ws, size_t ws_size,
                              hipStream_t stream) {
  const float* S = (const float*)d_in[0];   // [8192, 256] fp32
  const float* V = (const float*)d_in[1];   // [8192, 256] fp32
  float* O = (float*)d_out;                 // [8192, 8192] fp32

  unsigned short* P  = (unsigned short*)d_ws;          // 4 MB bf16 softmax(S)
  unsigned short* Vb = P + (size_t)NROW * D_DIM;       // 4 MB bf16 V

  softmax_rows<<<NROW / 4, 256, 0, stream>>>(S, P);
  cast_v<<<(NROW * D_DIM / 4) / 256, 256, 0, stream>>>(V, Vb);
  gemm_bt<<<dim3(NROW / 128, NROW / 128), 256, 0, stream>>>(P, Vb, O);
}